// Round 20
// baseline (189.294 us; speedup 1.0000x reference)
//
#include <hip/hip_runtime.h>
#include <hip/hip_bf16.h>
#include <math.h>

#define MAXDEG 64
#define MAXCHUNK 6400   // max dst-slice size for LDS histogram/cursor (25.6 KB)
#define NCH 64          // edge-chunks per slice

__device__ __forceinline__ float lrelu(float v) { return v > 0.0f ? v : 0.2f * v; }
__device__ __forceinline__ unsigned short bfenc(float f) {
  __hip_bfloat16 h = __float2bfloat16(f);
  return *(unsigned short*)&h;
}
__device__ __forceinline__ float bfdec(unsigned short u) {
  return __bfloat162float(*(__hip_bfloat16*)&u);
}

// ---- prep: cnt init (1 = self-loop fold; pad 0; used by fallback) + att fold (block 0)
__global__ void prep_kernel(int4* __restrict__ cnt4, int n4, int N,
                            const float* __restrict__ W, const float* __restrict__ att_src,
                            const float* __restrict__ att_dst, float* __restrict__ wsrc,
                            float* __restrict__ wdst) {
  int idx = blockIdx.x * 256 + threadIdx.x;
  for (int i = idx; i < n4; i += gridDim.x * 256) {
    int base = i * 4;
    int4 v;
    v.x = (base < N) ? 1 : 0;
    v.y = (base + 1 < N) ? 1 : 0;
    v.z = (base + 2 < N) ? 1 : 0;
    v.w = (base + 3 < N) ? 1 : 0;
    cnt4[i] = v;
  }
  if (blockIdx.x == 0) {
    int t = threadIdx.x;  // h = t>>6, k = t&63
    int h = t >> 6, k = t & 63;
    const float* wrow = W + (size_t)k * 256 + h * 64;
    const float* as = att_src + h * 64;
    const float* ad = att_dst + h * 64;
    float ss = 0.f, sd = 0.f;
#pragma unroll
    for (int c = 0; c < 64; ++c) {
      float w = wrow[c];
      ss = fmaf(w, as[c], ss);
      sd = fmaf(w, ad[c], sd);
    }
    wsrc[k * 4 + h] = ss;
    wdst[k * 4 + h] = sd;
  }
}

// ---- histpart: 8 dst-slices x NCH edge-chunks (blockIdx = p*8 + s);
// LDS-privatized, zero global atomics [r16]
__global__ __launch_bounds__(256) void histpart_kernel(
    const int* __restrict__ ei, int* __restrict__ cntpart, int E, int N, int chunkN) {
  __shared__ int h[MAXCHUNK];
  int s = blockIdx.x & 7, p = blockIdx.x >> 3;
  int lo = s * chunkN;
  int hi = lo + chunkN; if (hi > N) hi = N;
  for (int i = threadIdx.x; i < chunkN; i += 256) h[i] = 0;
  __syncthreads();
  int E4 = E >> 2;
  int c0 = (int)(((long long)p * E4) >> 6);
  int c1 = (int)(((long long)(p + 1) * E4) >> 6);
  const int4* d4p = (const int4*)(ei + E);
  for (int i = c0 + threadIdx.x; i < c1; i += 256) {
    int4 d = d4p[i];
    if (d.x >= lo && d.x < hi) atomicAdd(&h[d.x - lo], 1);
    if (d.y >= lo && d.y < hi) atomicAdd(&h[d.y - lo], 1);
    if (d.z >= lo && d.z < hi) atomicAdd(&h[d.z - lo], 1);
    if (d.w >= lo && d.w < hi) atomicAdd(&h[d.w - lo], 1);
  }
  __syncthreads();
  int* out = cntpart + (size_t)blockIdx.x * chunkN;
  for (int i = threadIdx.x; i < chunkN; i += 256) out[i] = h[i];
}

// ---- mergepfx: per bin, exclusive-prefix the NCH chunk partials in place;
// cnt[bin] = total + 1 (self-loop). Block (s,p) lives at blockIdx = p*8+s,
// so base = cntpart + s*chunkN, stride per p = 8*chunkN.   [BUGFIX r19]
__global__ void mergepfx_kernel(int* __restrict__ cntpart, int* __restrict__ cnt,
                                int N, int chunkN, int nbins) {
  int bin = blockIdx.x * 256 + threadIdx.x;
  if (bin >= nbins) return;
  if (bin < N) {
    int s = bin / chunkN;
    int i = bin - s * chunkN;
    int* base = cntpart + (size_t)s * chunkN + i;
    int run = 0;
    for (int p = 0; p < NCH; ++p) {
      size_t o = ((size_t)p << 3) * chunkN;  // block (s, p) at blockIdx p*8+s
      int v = base[o];
      base[o] = run;
      run += v;
    }
    cnt[bin] = run + 1;
  } else {
    cnt[bin] = 0;
  }
}

// ---- nattn: per-node attention scalars + bf16 copy of x [proven r10]
__global__ void nattn_kernel(const float* __restrict__ x, const float4* __restrict__ wsrc4,
                             const float4* __restrict__ wdst4, float4* __restrict__ asrc4,
                             float4* __restrict__ adst4, __hip_bfloat16* __restrict__ xh,
                             int N) {
  int lane = threadIdx.x & 63;
  int n = blockIdx.x * 4 + (threadIdx.x >> 6);
  if (n >= N) return;
  float xv = x[(size_t)n * 64 + lane];
  xh[(size_t)n * 64 + lane] = __float2bfloat16(xv);
  float4 ws = wsrc4[lane], wd = wdst4[lane];
  float s0 = xv * ws.x, s1 = xv * ws.y, s2 = xv * ws.z, s3 = xv * ws.w;
  float d0 = xv * wd.x, d1 = xv * wd.y, d2 = xv * wd.z, d3 = xv * wd.w;
#pragma unroll
  for (int m = 1; m < 64; m <<= 1) {
    s0 += __shfl_xor(s0, m, 64); s1 += __shfl_xor(s1, m, 64);
    s2 += __shfl_xor(s2, m, 64); s3 += __shfl_xor(s3, m, 64);
    d0 += __shfl_xor(d0, m, 64); d1 += __shfl_xor(d1, m, 64);
    d2 += __shfl_xor(d2, m, 64); d3 += __shfl_xor(d3, m, 64);
  }
  if (lane == 0) {
    asrc4[n] = make_float4(s0, s1, s2, s3);
    adst4[n] = make_float4(d0, d1, d2, d3);
  }
}

// ---- fallback hist/scatter [proven]
__global__ void hist_kernel(const int* __restrict__ ei, int* __restrict__ counts, int E) {
  int e = blockIdx.x * 256 + threadIdx.x;
  if (e >= E) return;
  atomicAdd(&counts[ei[(size_t)E + e]], 1);
}

__global__ void scatter_kernel(const int* __restrict__ ei, int* __restrict__ cursor,
                               int* __restrict__ src_sorted, int E, int N) {
  int e = blockIdx.x * 256 + threadIdx.x;
  int ET = E + N;
  if (e >= ET) return;
  int src, dst;
  if (e < E) {
    src = ei[e];
    dst = ei[(size_t)E + e];
  } else {
    src = dst = e - E;
  }
  int pos = atomicAdd(&cursor[dst], 1);
  src_sorted[pos] = src;
}

// ---- scatterDA: place edges AND compute per-edge alphas (bf16x4).
// Block (slice=blk&7, chunk=blk>>3): LDS cursors from row+1+chunk-prefix.
__global__ __launch_bounds__(256) void scatterDA_kernel(
    const int* __restrict__ ei, const int* __restrict__ row,
    const int* __restrict__ cntpart, const float4* __restrict__ asrc4,
    const float4* __restrict__ adst4, int* __restrict__ srt,
    ushort4* __restrict__ alpha4, int E, int N, int chunkN) {
  __shared__ int cur[MAXCHUNK];
  int slice = blockIdx.x & 7, p = blockIdx.x >> 3;
  int lo = slice * chunkN;
  int hi = lo + chunkN; if (hi > N) hi = N;
  const int* cp = cntpart + (size_t)blockIdx.x * chunkN;
  for (int i = threadIdx.x; i < chunkN; i += 256) {
    int bin = lo + i;
    cur[i] = (bin < N) ? row[bin] + 1 + cp[i] : 0;
  }
  __syncthreads();
  int E4 = E >> 2;
  int c0 = (int)(((long long)p * E4) >> 6);   // identical partition to histpart
  int c1 = (int)(((long long)(p + 1) * E4) >> 6);
  const int4* s4p = (const int4*)ei;
  const int4* d4p = (const int4*)(ei + E);
  for (int i = c0 + threadIdx.x; i < c1; i += 256) {
    int4 d = d4p[i];
    bool bx = (d.x >= lo && d.x < hi), by = (d.y >= lo && d.y < hi);
    bool bz = (d.z >= lo && d.z < hi), bw = (d.w >= lo && d.w < hi);
    if (!(bx || by || bz || bw)) continue;
    int4 sv = s4p[i];
#define PLACE(cond, dd, ss)                                              \
    if (cond) {                                                          \
      int q = atomicAdd(&cur[dd - lo], 1);                               \
      srt[q] = ss;                                                       \
      float4 as = asrc4[ss];                                             \
      float4 ad = adst4[dd];                                             \
      ushort4 u;                                                         \
      u.x = bfenc(__expf(lrelu(as.x + ad.x)));                           \
      u.y = bfenc(__expf(lrelu(as.y + ad.y)));                           \
      u.z = bfenc(__expf(lrelu(as.z + ad.z)));                           \
      u.w = bfenc(__expf(lrelu(as.w + ad.w)));                           \
      alpha4[q] = u;                                                     \
    }
    PLACE(bx, d.x, sv.x)
    PLACE(by, d.y, sv.y)
    PLACE(bz, d.z, sv.z)
    PLACE(bw, d.w, sv.w)
#undef PLACE
  }
}

// ---- scanABC (ntiles<=256) [r14] + self-loop srt + self-loop alpha
__global__ void scanABC_kernel(const int* __restrict__ cnt, int* __restrict__ row,
                               int* __restrict__ cur, int* __restrict__ srt,
                               const float4* __restrict__ asrc4,
                               const float4* __restrict__ adst4,
                               ushort4* __restrict__ alpha4,
                               int N, int ntiles, int writeSelf) {
  __shared__ int tl[256];
  __shared__ int part[256];
  int b = blockIdx.x, t = threadIdx.x;
  int s = 0;
  if (t < ntiles) {
    const int4* c4 = (const int4*)cnt + t * 64;
    for (int i = 0; i < 64; ++i) {
      int4 v = c4[i];
      s += v.x + v.y + v.z + v.w;
    }
  }
  tl[t] = s;
  __syncthreads();
  for (int d = 1; d < 256; d <<= 1) {
    int u = (t >= d) ? tl[t - d] : 0;
    __syncthreads();
    tl[t] += u;
    __syncthreads();
  }
  int tileoff = (b == 0) ? 0 : tl[b - 1];
  int idx = b * 256 + t;
  int c = (idx < N) ? cnt[idx] : 0;
  part[t] = c;
  __syncthreads();
  for (int d = 1; d < 256; d <<= 1) {
    int u = (t >= d) ? part[t - d] : 0;
    __syncthreads();
    part[t] += u;
    __syncthreads();
  }
  int exc = part[t] - c + tileoff;
  if (idx < N) {
    row[idx] = exc;
    cur[idx] = exc;
    if (writeSelf) {
      srt[exc] = idx;                     // self-loop occupies slot 0 of segment
      float4 as = asrc4[idx];
      float4 ad = adst4[idx];
      ushort4 u;
      u.x = bfenc(__expf(lrelu(as.x + ad.x)));
      u.y = bfenc(__expf(lrelu(as.y + ad.y)));
      u.z = bfenc(__expf(lrelu(as.z + ad.z)));
      u.w = bfenc(__expf(lrelu(as.w + ad.w)));
      alpha4[exc] = u;
    }
    if (idx == N - 1) row[N] = exc + c;
  }
}

// ---- scanA/B/C fallback for ntiles > 256 [proven r5]
__global__ void scanA_kernel(const int* __restrict__ cnt, int* __restrict__ tsum, int N) {
  int b = blockIdx.x, t = threadIdx.x;
  int idx = b * 256 + t;
  int v = (idx < N) ? cnt[idx] : 0;
#pragma unroll
  for (int m = 1; m < 64; m <<= 1) v += __shfl_xor(v, m, 64);
  __shared__ int ws[4];
  if ((t & 63) == 0) ws[t >> 6] = v;
  __syncthreads();
  if (t == 0) tsum[b] = ws[0] + ws[1] + ws[2] + ws[3];
}

__global__ void scanB_kernel(int* __restrict__ tsum, int ntiles) {
  __shared__ int part[256];
  int t = threadIdx.x;
  int carry = 0;
  for (int b0 = 0; b0 < ntiles; b0 += 256) {
    int idx = b0 + t;
    int v = (idx < ntiles) ? tsum[idx] : 0;
    part[t] = v;
    __syncthreads();
    for (int d = 1; d < 256; d <<= 1) {
      int u = (t >= d) ? part[t - d] : 0;
      __syncthreads();
      part[t] += u;
      __syncthreads();
    }
    if (idx < ntiles) tsum[idx] = part[t] - v + carry;
    carry += part[255];
    __syncthreads();
  }
}

__global__ void scanC_kernel(const int* __restrict__ cnt, const int* __restrict__ tsum,
                             int* __restrict__ row, int* __restrict__ cur, int N) {
  __shared__ int part[256];
  int b = blockIdx.x, t = threadIdx.x;
  int idx = b * 256 + t;
  int c = (idx < N) ? cnt[idx] : 0;
  part[t] = c;
  __syncthreads();
  for (int d = 1; d < 256; d <<= 1) {
    int u = (t >= d) ? part[t - d] : 0;
    __syncthreads();
    part[t] += u;
    __syncthreads();
  }
  int exc = part[t] - c + tsum[b];
  if (idx < N) {
    row[idx] = exc;
    cur[idx] = exc;
    if (idx == N - 1) row[N] = exc + c;
  }
}

// ---- agg2: alpha-based aggregation. Pass A streams alpha_s (sequential 8B);
// Pass B broadcasts alpha + gathers xh rows. No asrc gathers, no exps, no LDS.
__global__ __launch_bounds__(256) void agg2_kernel(
    const int* __restrict__ srt, const int* __restrict__ row,
    const ushort4* __restrict__ alpha4, const __hip_bfloat16* __restrict__ xh,
    __hip_bfloat16* __restrict__ agg, int N) {
  int t = threadIdx.x, w = t >> 6, lane = t & 63;
  int n = blockIdx.x * 4 + w;
  if (n >= N) return;
  int start = row[n], end = row[n + 1];
  int deg = end - start;
  // Pass A: per-lane strided sum of stored alphas (sequential reads)
  float t0 = 0.f, t1 = 0.f, t2 = 0.f, t3 = 0.f;
  for (int j = lane; j < deg; j += 64) {
    ushort4 u = alpha4[start + j];
    t0 += bfdec(u.x); t1 += bfdec(u.y); t2 += bfdec(u.z); t3 += bfdec(u.w);
  }
#pragma unroll
  for (int m = 1; m < 64; m <<= 1) {
    t0 += __shfl_xor(t0, m, 64);
    t1 += __shfl_xor(t1, m, 64);
    t2 += __shfl_xor(t2, m, 64);
    t3 += __shfl_xor(t3, m, 64);
  }
  float r0 = 0.25f / (t0 + 1e-16f), r1 = 0.25f / (t1 + 1e-16f);
  float r2 = 0.25f / (t2 + 1e-16f), r3 = 0.25f / (t3 + 1e-16f);
  // Pass B: lane = channel; broadcast alpha + srt, gather xh rows
  float a0 = 0.f, a1 = 0.f, a2 = 0.f, a3 = 0.f;
  int j = 0;
  for (; j + 4 <= deg; j += 4) {
    int q0 = srt[start + j], q1 = srt[start + j + 1];
    int q2 = srt[start + j + 2], q3 = srt[start + j + 3];
    ushort4 u0 = alpha4[start + j], u1 = alpha4[start + j + 1];
    ushort4 u2 = alpha4[start + j + 2], u3 = alpha4[start + j + 3];
    float v0 = __bfloat162float(xh[(size_t)q0 * 64 + lane]);
    float v1 = __bfloat162float(xh[(size_t)q1 * 64 + lane]);
    float v2 = __bfloat162float(xh[(size_t)q2 * 64 + lane]);
    float v3 = __bfloat162float(xh[(size_t)q3 * 64 + lane]);
    a0 = fmaf(bfdec(u0.x), v0, a0); a1 = fmaf(bfdec(u0.y), v0, a1);
    a2 = fmaf(bfdec(u0.z), v0, a2); a3 = fmaf(bfdec(u0.w), v0, a3);
    a0 = fmaf(bfdec(u1.x), v1, a0); a1 = fmaf(bfdec(u1.y), v1, a1);
    a2 = fmaf(bfdec(u1.z), v1, a2); a3 = fmaf(bfdec(u1.w), v1, a3);
    a0 = fmaf(bfdec(u2.x), v2, a0); a1 = fmaf(bfdec(u2.y), v2, a1);
    a2 = fmaf(bfdec(u2.z), v2, a2); a3 = fmaf(bfdec(u2.w), v2, a3);
    a0 = fmaf(bfdec(u3.x), v3, a0); a1 = fmaf(bfdec(u3.y), v3, a1);
    a2 = fmaf(bfdec(u3.z), v3, a2); a3 = fmaf(bfdec(u3.w), v3, a3);
  }
  for (; j < deg; ++j) {
    int q0 = srt[start + j];
    ushort4 u0 = alpha4[start + j];
    float v0 = __bfloat162float(xh[(size_t)q0 * 64 + lane]);
    a0 = fmaf(bfdec(u0.x), v0, a0); a1 = fmaf(bfdec(u0.y), v0, a1);
    a2 = fmaf(bfdec(u0.z), v0, a2); a3 = fmaf(bfdec(u0.w), v0, a3);
  }
  __hip_bfloat16* ao = agg + (size_t)n * 256;
  ao[lane] = __float2bfloat16(a0 * r0);
  ao[64 + lane] = __float2bfloat16(a1 * r1);
  ao[128 + lane] = __float2bfloat16(a2 * r2);
  ao[192 + lane] = __float2bfloat16(a3 * r3);
}

// ---- aggF: fallback asrc-gather aggregation [proven r13]
__global__ __launch_bounds__(256) void aggF_kernel(
    const int* __restrict__ srt, const int* __restrict__ row,
    const float4* __restrict__ asrc4, const float4* __restrict__ adst4,
    const __hip_bfloat16* __restrict__ xh, __hip_bfloat16* __restrict__ agg, int N) {
  __shared__ float4 alL[4][MAXDEG];
  __shared__ int slL[4][MAXDEG];
  int t = threadIdx.x, w = t >> 6, lane = t & 63;
  int n = blockIdx.x * 4 + w;
  if (n >= N) return;
  int start = row[n], end = row[n + 1];
  int deg = end - start;
  float4 ad = adst4[n];
  float t0 = 0.f, t1 = 0.f, t2 = 0.f, t3 = 0.f;
  if (deg <= MAXDEG) {
    for (int b = 0; b < deg; b += 64) {
      if (b + lane < deg) {
        int sl = srt[start + b + lane];
        float4 as = asrc4[sl];
        float4 e;
        e.x = __expf(lrelu(as.x + ad.x));
        e.y = __expf(lrelu(as.y + ad.y));
        e.z = __expf(lrelu(as.z + ad.z));
        e.w = __expf(lrelu(as.w + ad.w));
        alL[w][b + lane] = e;
        slL[w][b + lane] = sl;
        t0 += e.x; t1 += e.y; t2 += e.z; t3 += e.w;
      }
    }
  } else {
    for (int b = start; b < end; b += 64) {
      int idx = b + lane;
      if (idx < end) {
        int sl = srt[idx];
        float4 as = asrc4[sl];
        t0 += __expf(lrelu(as.x + ad.x));
        t1 += __expf(lrelu(as.y + ad.y));
        t2 += __expf(lrelu(as.z + ad.z));
        t3 += __expf(lrelu(as.w + ad.w));
      }
    }
  }
#pragma unroll
  for (int m = 1; m < 64; m <<= 1) {
    t0 += __shfl_xor(t0, m, 64);
    t1 += __shfl_xor(t1, m, 64);
    t2 += __shfl_xor(t2, m, 64);
    t3 += __shfl_xor(t3, m, 64);
  }
  float r0 = 0.25f / (t0 + 1e-16f), r1 = 0.25f / (t1 + 1e-16f);
  float r2 = 0.25f / (t2 + 1e-16f), r3 = 0.25f / (t3 + 1e-16f);
  float a0 = 0.f, a1 = 0.f, a2 = 0.f, a3 = 0.f;
  if (deg <= MAXDEG) {
    for (int j = 0; j < deg; ++j) {
      float4 e0 = alL[w][j];
      int q0 = slL[w][j];
      float v0 = __bfloat162float(xh[(size_t)q0 * 64 + lane]);
      a0 = fmaf(e0.x, v0, a0); a1 = fmaf(e0.y, v0, a1);
      a2 = fmaf(e0.z, v0, a2); a3 = fmaf(e0.w, v0, a3);
    }
  } else {
    for (int b = start; b < end; b += 64) {
      int cnt = end - b;
      if (cnt > 64) cnt = 64;
      int idx = b + lane;
      int sl = 0;
      float e0 = 0.f, e1 = 0.f, e2 = 0.f, e3 = 0.f;
      if (idx < end) {
        sl = srt[idx];
        float4 as = asrc4[sl];
        e0 = __expf(lrelu(as.x + ad.x));
        e1 = __expf(lrelu(as.y + ad.y));
        e2 = __expf(lrelu(as.z + ad.z));
        e3 = __expf(lrelu(as.w + ad.w));
      }
      for (int j = 0; j < cnt; ++j) {
        int sj = __shfl(sl, j, 64);
        float b0 = __shfl(e0, j, 64), b1 = __shfl(e1, j, 64);
        float b2 = __shfl(e2, j, 64), b3 = __shfl(e3, j, 64);
        float v = __bfloat162float(xh[(size_t)sj * 64 + lane]);
        a0 = fmaf(b0, v, a0); a1 = fmaf(b1, v, a1);
        a2 = fmaf(b2, v, a2); a3 = fmaf(b3, v, a3);
      }
    }
  }
  __hip_bfloat16* ao = agg + (size_t)n * 256;
  ao[lane] = __float2bfloat16(a0 * r0);
  ao[64 + lane] = __float2bfloat16(a1 * r1);
  ao[128 + lane] = __float2bfloat16(a2 * r2);
  ao[192 + lane] = __float2bfloat16(a3 * r3);
}

// ---- Projection: bf16 agg -> f32 LDS [proven r13]
__global__ __launch_bounds__(256) void proj_kernel(
    const __hip_bfloat16* __restrict__ agg, const float* __restrict__ W,
    const float* __restrict__ bias, float* __restrict__ out, int N) {
  __shared__ float aggL[4][256];
  __shared__ float pL[4][4][64];
  int t = threadIdx.x, w = t >> 6, lane = t & 63;
  float Wreg[64];
#pragma unroll
  for (int k = 0; k < 64; ++k) Wreg[k] = W[(size_t)k * 256 + w * 64 + lane];
  float bv = bias[lane];
  int ngroups = (N + 3) >> 2;
  for (int g = blockIdx.x; g < ngroups; g += gridDim.x) {
    int n0 = g * 4;
    __syncthreads();
    {
      int nn = n0 + w;
      if (nn < N) {
        ushort4 u = ((const ushort4*)(agg + (size_t)nn * 256))[t & 63];
        float4 f;
        f.x = bfdec(u.x); f.y = bfdec(u.y); f.z = bfdec(u.z); f.w = bfdec(u.w);
        *(float4*)&aggL[w][(t & 63) * 4] = f;
      } else {
        *(float4*)&aggL[w][(t & 63) * 4] = make_float4(0.f, 0.f, 0.f, 0.f);
      }
    }
    __syncthreads();
    float acc0 = 0.f, acc1 = 0.f, acc2 = 0.f, acc3 = 0.f;
#pragma unroll
    for (int k4 = 0; k4 < 16; ++k4) {
      float4 av0 = *(const float4*)&aggL[0][w * 64 + k4 * 4];
      float4 av1 = *(const float4*)&aggL[1][w * 64 + k4 * 4];
      float4 av2 = *(const float4*)&aggL[2][w * 64 + k4 * 4];
      float4 av3 = *(const float4*)&aggL[3][w * 64 + k4 * 4];
      float w0 = Wreg[k4 * 4 + 0], w1 = Wreg[k4 * 4 + 1];
      float w2 = Wreg[k4 * 4 + 2], w3 = Wreg[k4 * 4 + 3];
      acc0 = fmaf(av0.x, w0, acc0); acc0 = fmaf(av0.y, w1, acc0);
      acc0 = fmaf(av0.z, w2, acc0); acc0 = fmaf(av0.w, w3, acc0);
      acc1 = fmaf(av1.x, w0, acc1); acc1 = fmaf(av1.y, w1, acc1);
      acc1 = fmaf(av1.z, w2, acc1); acc1 = fmaf(av1.w, w3, acc1);
      acc2 = fmaf(av2.x, w0, acc2); acc2 = fmaf(av2.y, w1, acc2);
      acc2 = fmaf(av2.z, w2, acc2); acc2 = fmaf(av2.w, w3, acc2);
      acc3 = fmaf(av3.x, w0, acc3); acc3 = fmaf(av3.y, w1, acc3);
      acc3 = fmaf(av3.z, w2, acc3); acc3 = fmaf(av3.w, w3, acc3);
    }
    pL[w][0][lane] = acc0;
    pL[w][1][lane] = acc1;
    pL[w][2][lane] = acc2;
    pL[w][3][lane] = acc3;
    __syncthreads();
    int nn = n0 + w;
    if (nn < N) {
      out[(size_t)nn * 64 + lane] = pL[0][w][lane] + pL[1][w][lane] +
                                    pL[2][w][lane] + pL[3][w][lane] + bv;
    }
  }
}

extern "C" void kernel_launch(void* const* d_in, const int* in_sizes, int n_in,
                              void* d_out, int out_size, void* d_ws, size_t ws_size,
                              hipStream_t stream) {
  const float* meta_x = (const float*)d_in[0];
  const int* ei = (const int*)d_in[1];  // int32 edge index [2,E] flat
  const float* W = (const float*)d_in[2];
  const float* att_src = (const float*)d_in[3];
  const float* att_dst = (const float*)d_in[4];
  const float* bias = (const float*)d_in[5];
  float* out = (float*)d_out;

  int N = in_sizes[0] / 64;
  int E = in_sizes[1] / 2;
  int ET = E + N;
  int ntiles = (N + 255) / 256;
  int chunkN = (N + 7) / 8;

  char* ws = (char*)d_ws;
  size_t off = 0;
  auto alloc = [&](size_t bytes) {
    size_t o = off;
    off += (bytes + 255) & ~(size_t)255;
    return o;
  };
  size_t o_wsrc = alloc(64 * 4 * sizeof(float));
  size_t o_wdst = alloc(64 * 4 * sizeof(float));
  size_t o_asrc = alloc((size_t)N * 4 * sizeof(float));
  size_t o_adst = alloc((size_t)N * 4 * sizeof(float));
  size_t o_cnt = alloc((size_t)ntiles * 256 * sizeof(int));
  size_t o_row = alloc(((size_t)N + 1) * sizeof(int));
  size_t o_cur = alloc((size_t)N * sizeof(int));
  size_t o_srt = alloc((size_t)ET * sizeof(int));
  size_t o_ts = alloc((size_t)ntiles * sizeof(int));
  size_t o_cp = alloc((size_t)8 * NCH * chunkN * sizeof(int));     // 12.8 MB partials
  size_t o_al = alloc((size_t)ET * sizeof(ushort4));               // 6.8 MB alphas
  size_t o_xh = alloc((size_t)N * 64 * sizeof(__hip_bfloat16));    // 6.4 MB
  size_t o_agg = alloc((size_t)N * 256 * sizeof(__hip_bfloat16));  // 25.6 MB
  (void)ws_size;

  float* wsrc = (float*)(ws + o_wsrc);
  float* wdst = (float*)(ws + o_wdst);
  float4* asrc4 = (float4*)(ws + o_asrc);
  float4* adst4 = (float4*)(ws + o_adst);
  int* cnt = (int*)(ws + o_cnt);
  int* row = (int*)(ws + o_row);
  int* cur = (int*)(ws + o_cur);
  int* srt = (int*)(ws + o_srt);
  int* tsum = (int*)(ws + o_ts);
  int* cntpart = (int*)(ws + o_cp);
  ushort4* alpha4 = (ushort4*)(ws + o_al);
  __hip_bfloat16* xh = (__hip_bfloat16*)(ws + o_xh);
  __hip_bfloat16* aggp = (__hip_bfloat16*)(ws + o_agg);

  int n4 = ntiles * 64;
  prep_kernel<<<64, 256, 0, stream>>>((int4*)cnt, n4, N, W, att_src, att_dst, wsrc, wdst);

  bool ldsPath = ((E & 3) == 0) && (chunkN <= MAXCHUNK) && (ntiles <= 256);
  if (ldsPath) {
    histpart_kernel<<<8 * NCH, 256, 0, stream>>>(ei, cntpart, E, N, chunkN);
    nattn_kernel<<<(N + 3) / 4, 256, 0, stream>>>(meta_x, (const float4*)wsrc,
                                                  (const float4*)wdst, asrc4, adst4, xh, N);
    mergepfx_kernel<<<ntiles, 256, 0, stream>>>(cntpart, cnt, N, chunkN, ntiles * 256);
    scanABC_kernel<<<ntiles, 256, 0, stream>>>(cnt, row, cur, srt, asrc4, adst4,
                                               alpha4, N, ntiles, 1);
    scatterDA_kernel<<<8 * NCH, 256, 0, stream>>>(ei, row, cntpart, asrc4, adst4,
                                                  srt, alpha4, E, N, chunkN);
    agg2_kernel<<<(N + 3) / 4, 256, 0, stream>>>(srt, row, alpha4, xh, aggp, N);
  } else {
    nattn_kernel<<<(N + 3) / 4, 256, 0, stream>>>(meta_x, (const float4*)wsrc,
                                                  (const float4*)wdst, asrc4, adst4, xh, N);
    hist_kernel<<<(E + 255) / 256, 256, 0, stream>>>(ei, cnt, E);
    if (ntiles <= 256) {
      scanABC_kernel<<<ntiles, 256, 0, stream>>>(cnt, row, cur, srt, asrc4, adst4,
                                                 alpha4, N, ntiles, 0);
    } else {
      scanA_kernel<<<ntiles, 256, 0, stream>>>(cnt, tsum, N);
      scanB_kernel<<<1, 256, 0, stream>>>(tsum, ntiles);
      scanC_kernel<<<ntiles, 256, 0, stream>>>(cnt, tsum, row, cur, N);
    }
    scatter_kernel<<<(ET + 255) / 256, 256, 0, stream>>>(ei, cur, srt, E, N);
    aggF_kernel<<<(N + 3) / 4, 256, 0, stream>>>(srt, row, asrc4, adst4, xh, aggp, N);
  }

  int ngroups = (N + 3) / 4;
  int pgrid = ngroups < 1024 ? ngroups : 1024;
  proj_kernel<<<pgrid, 256, 0, stream>>>(aggp, W, bias, out, N);
}

// Round 21
// 168.047 us; speedup vs baseline: 1.1264x; 1.1264x over previous
//
#include <hip/hip_runtime.h>
#include <hip/hip_bf16.h>
#include <math.h>

#define MAXDEG 64
#define MAXCHUNK 6400   // max dst-slice size for LDS histogram (25.6 KB)

__device__ __forceinline__ float lrelu(float v) { return v > 0.0f ? v : 0.2f * v; }

// ---- prep: cnt init (1 = self-loop fold; pad 0) + att fold (block 0)
__global__ void prep_kernel(int4* __restrict__ cnt4, int n4, int N,
                            const float* __restrict__ W, const float* __restrict__ att_src,
                            const float* __restrict__ att_dst, float* __restrict__ wsrc,
                            float* __restrict__ wdst) {
  int idx = blockIdx.x * 256 + threadIdx.x;
  for (int i = idx; i < n4; i += gridDim.x * 256) {
    int base = i * 4;
    int4 v;
    v.x = (base < N) ? 1 : 0;
    v.y = (base + 1 < N) ? 1 : 0;
    v.z = (base + 2 < N) ? 1 : 0;
    v.w = (base + 3 < N) ? 1 : 0;
    cnt4[i] = v;
  }
  if (blockIdx.x == 0) {
    int t = threadIdx.x;  // h = t>>6, k = t&63
    int h = t >> 6, k = t & 63;
    const float* wrow = W + (size_t)k * 256 + h * 64;
    const float* as = att_src + h * 64;
    const float* ad = att_dst + h * 64;
    float ss = 0.f, sd = 0.f;
#pragma unroll
    for (int c = 0; c < 64; ++c) {
      float w = wrow[c];
      ss = fmaf(w, as[c], ss);
      sd = fmaf(w, ad[c], sd);
    }
    wsrc[k * 4 + h] = ss;
    wdst[k * 4 + h] = sd;
  }
}

// ---- histpart: 8 dst-slices x 32 edge-chunks; LDS-privatized histogram, NO global
// atomics (device atomics are memory-side RMW on CDNA4; LDS atomics are on-CU). [r16]
__global__ __launch_bounds__(256) void histpart_kernel(
    const int* __restrict__ ei, int* __restrict__ cntpart, int E, int N, int chunkN) {
  __shared__ int h[MAXCHUNK];
  int s = blockIdx.x >> 5, p = blockIdx.x & 31;
  int lo = s * chunkN;
  int hi = lo + chunkN; if (hi > N) hi = N;
  for (int i = threadIdx.x; i < chunkN; i += 256) h[i] = 0;
  __syncthreads();
  int E4 = E >> 2;
  int c0 = (int)(((long long)p * E4) >> 5);
  int c1 = (int)(((long long)(p + 1) * E4) >> 5);
  const int4* d4p = (const int4*)(ei + E);
  for (int i = c0 + threadIdx.x; i < c1; i += 256) {
    int4 d = d4p[i];
    if (d.x >= lo && d.x < hi) atomicAdd(&h[d.x - lo], 1);
    if (d.y >= lo && d.y < hi) atomicAdd(&h[d.y - lo], 1);
    if (d.z >= lo && d.z < hi) atomicAdd(&h[d.z - lo], 1);
    if (d.w >= lo && d.w < hi) atomicAdd(&h[d.w - lo], 1);
  }
  __syncthreads();
  int* out = cntpart + (size_t)blockIdx.x * chunkN;
  for (int i = threadIdx.x; i < chunkN; i += 256) out[i] = h[i];
}

// ---- merge: cnt[bin] = 1 (self-loop) + sum of 32 partials; 0 for pad bins. [r16]
__global__ void merge_kernel(const int* __restrict__ cntpart, int* __restrict__ cnt,
                             int N, int chunkN, int nbins) {
  int bin = blockIdx.x * 256 + threadIdx.x;
  if (bin >= nbins) return;
  if (bin < N) {
    int s = bin / chunkN;
    int i = bin - s * chunkN;
    const int* base = cntpart + (size_t)(s * 32) * chunkN + i;
    int sum = 1;
#pragma unroll
    for (int p = 0; p < 32; ++p) sum += base[(size_t)p * chunkN];
    cnt[bin] = sum;
  } else {
    cnt[bin] = 0;
  }
}

// ---- nattn: per-node attention scalars + bf16 copy of x [proven r10]
__global__ void nattn_kernel(const float* __restrict__ x, const float4* __restrict__ wsrc4,
                             const float4* __restrict__ wdst4, float4* __restrict__ asrc4,
                             float4* __restrict__ adst4, __hip_bfloat16* __restrict__ xh,
                             int N) {
  int lane = threadIdx.x & 63;
  int n = blockIdx.x * 4 + (threadIdx.x >> 6);
  if (n >= N) return;
  float xv = x[(size_t)n * 64 + lane];
  xh[(size_t)n * 64 + lane] = __float2bfloat16(xv);
  float4 ws = wsrc4[lane], wd = wdst4[lane];
  float s0 = xv * ws.x, s1 = xv * ws.y, s2 = xv * ws.z, s3 = xv * ws.w;
  float d0 = xv * wd.x, d1 = xv * wd.y, d2 = xv * wd.z, d3 = xv * wd.w;
#pragma unroll
  for (int m = 1; m < 64; m <<= 1) {
    s0 += __shfl_xor(s0, m, 64); s1 += __shfl_xor(s1, m, 64);
    s2 += __shfl_xor(s2, m, 64); s3 += __shfl_xor(s3, m, 64);
    d0 += __shfl_xor(d0, m, 64); d1 += __shfl_xor(d1, m, 64);
    d2 += __shfl_xor(d2, m, 64); d3 += __shfl_xor(d3, m, 64);
  }
  if (lane == 0) {
    asrc4[n] = make_float4(s0, s1, s2, s3);
    adst4[n] = make_float4(d0, d1, d2, d3);
  }
}

// ---- fallback hist (edges only; self-loops in init) / scatter [proven]
__global__ void hist_kernel(const int* __restrict__ ei, int* __restrict__ counts, int E) {
  int e = blockIdx.x * 256 + threadIdx.x;
  if (e >= E) return;
  atomicAdd(&counts[ei[(size_t)E + e]], 1);
}

__global__ void scatter_kernel(const int* __restrict__ ei, int* __restrict__ cursor,
                               int* __restrict__ src_sorted, int E, int N) {
  int e = blockIdx.x * 256 + threadIdx.x;
  int ET = E + N;
  if (e >= ET) return;
  int src, dst;
  if (e < E) {
    src = ei[e];
    dst = ei[(size_t)E + e];
  } else {
    src = dst = e - E;
  }
  int pos = atomicAdd(&cursor[dst], 1);
  src_sorted[pos] = src;
}

// ---- XCD-sliced scatter [proven r9]
__global__ void scatter8_kernel(const int* __restrict__ ei, int* __restrict__ cursor,
                                int* __restrict__ srt, int E, int N) {
  int slice = blockIdx.x & 7;
  int bid = blockIdx.x >> 3;
  int nb = gridDim.x >> 3;
  int chunk = (N + 7) >> 3;
  int lo = slice * chunk;
  int hi = lo + chunk; if (hi > N) hi = N;
  int E4 = E >> 2;
  const int4* s4p = (const int4*)ei;
  const int4* d4p = (const int4*)(ei + E);
  int stride = nb * 256;
  for (int i = bid * 256 + threadIdx.x; i < E4; i += stride) {
    int4 d4 = d4p[i];
    bool bx = (d4.x >= lo && d4.x < hi), by = (d4.y >= lo && d4.y < hi);
    bool bz = (d4.z >= lo && d4.z < hi), bw = (d4.w >= lo && d4.w < hi);
    if (!(bx || by || bz || bw)) continue;
    int4 s4 = s4p[i];
    if (bx) { int p = atomicAdd(&cursor[d4.x], 1); srt[p] = s4.x; }
    if (by) { int p = atomicAdd(&cursor[d4.y], 1); srt[p] = s4.y; }
    if (bz) { int p = atomicAdd(&cursor[d4.z], 1); srt[p] = s4.z; }
    if (bw) { int p = atomicAdd(&cursor[d4.w], 1); srt[p] = s4.w; }
  }
  for (int n = lo + bid * 256 + threadIdx.x; n < hi; n += stride) {
    int p = atomicAdd(&cursor[n], 1);
    srt[p] = n;
  }
}

// ---- scanABC (ntiles<=256) [proven r14]
__global__ void scanABC_kernel(const int* __restrict__ cnt, int* __restrict__ row,
                               int* __restrict__ cur, int N, int ntiles) {
  __shared__ int tl[256];
  __shared__ int part[256];
  int b = blockIdx.x, t = threadIdx.x;
  int s = 0;
  if (t < ntiles) {
    const int4* c4 = (const int4*)cnt + t * 64;
    for (int i = 0; i < 64; ++i) {
      int4 v = c4[i];
      s += v.x + v.y + v.z + v.w;
    }
  }
  tl[t] = s;
  __syncthreads();
  for (int d = 1; d < 256; d <<= 1) {
    int u = (t >= d) ? tl[t - d] : 0;
    __syncthreads();
    tl[t] += u;
    __syncthreads();
  }
  int tileoff = (b == 0) ? 0 : tl[b - 1];
  int idx = b * 256 + t;
  int c = (idx < N) ? cnt[idx] : 0;
  part[t] = c;
  __syncthreads();
  for (int d = 1; d < 256; d <<= 1) {
    int u = (t >= d) ? part[t - d] : 0;
    __syncthreads();
    part[t] += u;
    __syncthreads();
  }
  int exc = part[t] - c + tileoff;
  if (idx < N) {
    row[idx] = exc;
    cur[idx] = exc;
    if (idx == N - 1) row[N] = exc + c;
  }
}

// ---- scanA/B/C fallback for ntiles > 256 [proven r5]
__global__ void scanA_kernel(const int* __restrict__ cnt, int* __restrict__ tsum, int N) {
  int b = blockIdx.x, t = threadIdx.x;
  int idx = b * 256 + t;
  int v = (idx < N) ? cnt[idx] : 0;
#pragma unroll
  for (int m = 1; m < 64; m <<= 1) v += __shfl_xor(v, m, 64);
  __shared__ int ws[4];
  if ((t & 63) == 0) ws[t >> 6] = v;
  __syncthreads();
  if (t == 0) tsum[b] = ws[0] + ws[1] + ws[2] + ws[3];
}

__global__ void scanB_kernel(int* __restrict__ tsum, int ntiles) {
  __shared__ int part[256];
  int t = threadIdx.x;
  int carry = 0;
  for (int b0 = 0; b0 < ntiles; b0 += 256) {
    int idx = b0 + t;
    int v = (idx < ntiles) ? tsum[idx] : 0;
    part[t] = v;
    __syncthreads();
    for (int d = 1; d < 256; d <<= 1) {
      int u = (t >= d) ? part[t - d] : 0;
      __syncthreads();
      part[t] += u;
      __syncthreads();
    }
    if (idx < ntiles) tsum[idx] = part[t] - v + carry;
    carry += part[255];
    __syncthreads();
  }
}

__global__ void scanC_kernel(const int* __restrict__ cnt, const int* __restrict__ tsum,
                             int* __restrict__ row, int* __restrict__ cur, int N) {
  __shared__ int part[256];
  int b = blockIdx.x, t = threadIdx.x;
  int idx = b * 256 + t;
  int c = (idx < N) ? cnt[idx] : 0;
  part[t] = c;
  __syncthreads();
  for (int d = 1; d < 256; d <<= 1) {
    int u = (t >= d) ? part[t - d] : 0;
    __syncthreads();
    part[t] += u;
    __syncthreads();
  }
  int exc = part[t] - c + tsum[b];
  if (idx < N) {
    row[idx] = exc;
    cur[idx] = exc;
    if (idx == N - 1) row[N] = exc + c;
  }
}

// ---- Aggregation: one wave per node, zero barriers; bf16 x; bf16 agg [proven r13]
__global__ __launch_bounds__(256) void agg_kernel(
    const int* __restrict__ srt, const int* __restrict__ row,
    const float4* __restrict__ asrc4, const float4* __restrict__ adst4,
    const __hip_bfloat16* __restrict__ xh, __hip_bfloat16* __restrict__ agg, int N) {
  __shared__ float4 alL[4][MAXDEG];  // 4096B
  __shared__ int slL[4][MAXDEG];     // 1024B
  int t = threadIdx.x, w = t >> 6, lane = t & 63;
  int n = blockIdx.x * 4 + w;
  if (n >= N) return;
  int start = row[n], end = row[n + 1];
  int deg = end - start;
  float4 ad = adst4[n];
  float t0 = 0.f, t1 = 0.f, t2 = 0.f, t3 = 0.f;
  if (deg <= MAXDEG) {
    for (int b = 0; b < deg; b += 64) {
      if (b + lane < deg) {
        int sl = srt[start + b + lane];
        float4 as = asrc4[sl];
        float4 e;
        e.x = __expf(lrelu(as.x + ad.x));
        e.y = __expf(lrelu(as.y + ad.y));
        e.z = __expf(lrelu(as.z + ad.z));
        e.w = __expf(lrelu(as.w + ad.w));
        alL[w][b + lane] = e;
        slL[w][b + lane] = sl;
        t0 += e.x; t1 += e.y; t2 += e.z; t3 += e.w;
      }
    }
  } else {
    for (int b = start; b < end; b += 64) {
      int idx = b + lane;
      if (idx < end) {
        int sl = srt[idx];
        float4 as = asrc4[sl];
        t0 += __expf(lrelu(as.x + ad.x));
        t1 += __expf(lrelu(as.y + ad.y));
        t2 += __expf(lrelu(as.z + ad.z));
        t3 += __expf(lrelu(as.w + ad.w));
      }
    }
  }
#pragma unroll
  for (int m = 1; m < 64; m <<= 1) {
    t0 += __shfl_xor(t0, m, 64);
    t1 += __shfl_xor(t1, m, 64);
    t2 += __shfl_xor(t2, m, 64);
    t3 += __shfl_xor(t3, m, 64);
  }
  float r0 = 0.25f / (t0 + 1e-16f), r1 = 0.25f / (t1 + 1e-16f);
  float r2 = 0.25f / (t2 + 1e-16f), r3 = 0.25f / (t3 + 1e-16f);
  float a0 = 0.f, a1 = 0.f, a2 = 0.f, a3 = 0.f;
  if (deg <= MAXDEG) {
    int j = 0;
    for (; j + 4 <= deg; j += 4) {
      float4 e0 = alL[w][j], e1 = alL[w][j + 1], e2 = alL[w][j + 2], e3 = alL[w][j + 3];
      int q0 = slL[w][j], q1 = slL[w][j + 1], q2 = slL[w][j + 2], q3 = slL[w][j + 3];
      float v0 = __bfloat162float(xh[(size_t)q0 * 64 + lane]);
      float v1 = __bfloat162float(xh[(size_t)q1 * 64 + lane]);
      float v2 = __bfloat162float(xh[(size_t)q2 * 64 + lane]);
      float v3 = __bfloat162float(xh[(size_t)q3 * 64 + lane]);
      a0 = fmaf(e0.x, v0, a0); a1 = fmaf(e0.y, v0, a1);
      a2 = fmaf(e0.z, v0, a2); a3 = fmaf(e0.w, v0, a3);
      a0 = fmaf(e1.x, v1, a0); a1 = fmaf(e1.y, v1, a1);
      a2 = fmaf(e1.z, v1, a2); a3 = fmaf(e1.w, v1, a3);
      a0 = fmaf(e2.x, v2, a0); a1 = fmaf(e2.y, v2, a1);
      a2 = fmaf(e2.z, v2, a2); a3 = fmaf(e2.w, v2, a3);
      a0 = fmaf(e3.x, v3, a0); a1 = fmaf(e3.y, v3, a1);
      a2 = fmaf(e3.z, v3, a2); a3 = fmaf(e3.w, v3, a3);
    }
    for (; j < deg; ++j) {
      float4 e0 = alL[w][j];
      int q0 = slL[w][j];
      float v0 = __bfloat162float(xh[(size_t)q0 * 64 + lane]);
      a0 = fmaf(e0.x, v0, a0); a1 = fmaf(e0.y, v0, a1);
      a2 = fmaf(e0.z, v0, a2); a3 = fmaf(e0.w, v0, a3);
    }
  } else {
    for (int b = start; b < end; b += 64) {
      int cnt = end - b;
      if (cnt > 64) cnt = 64;
      int idx = b + lane;
      int sl = 0;
      float e0 = 0.f, e1 = 0.f, e2 = 0.f, e3 = 0.f;
      if (idx < end) {
        sl = srt[idx];
        float4 as = asrc4[sl];
        e0 = __expf(lrelu(as.x + ad.x));
        e1 = __expf(lrelu(as.y + ad.y));
        e2 = __expf(lrelu(as.z + ad.z));
        e3 = __expf(lrelu(as.w + ad.w));
      }
      for (int j = 0; j < cnt; ++j) {
        int sj = __shfl(sl, j, 64);
        float b0 = __shfl(e0, j, 64), b1 = __shfl(e1, j, 64);
        float b2 = __shfl(e2, j, 64), b3 = __shfl(e3, j, 64);
        float v = __bfloat162float(xh[(size_t)sj * 64 + lane]);
        a0 = fmaf(b0, v, a0); a1 = fmaf(b1, v, a1);
        a2 = fmaf(b2, v, a2); a3 = fmaf(b3, v, a3);
      }
    }
  }
  __hip_bfloat16* ao = agg + (size_t)n * 256;
  ao[lane] = __float2bfloat16(a0 * r0);
  ao[64 + lane] = __float2bfloat16(a1 * r1);
  ao[128 + lane] = __float2bfloat16(a2 * r2);
  ao[192 + lane] = __float2bfloat16(a3 * r3);
}

// ---- Projection: bf16 agg -> f32 LDS [proven r13]
__global__ __launch_bounds__(256) void proj_kernel(
    const __hip_bfloat16* __restrict__ agg, const float* __restrict__ W,
    const float* __restrict__ bias, float* __restrict__ out, int N) {
  __shared__ float aggL[4][256];   // 4KB
  __shared__ float pL[4][4][64];   // 4KB
  int t = threadIdx.x, w = t >> 6, lane = t & 63;
  float Wreg[64];  // W[k, w*64 + lane]
#pragma unroll
  for (int k = 0; k < 64; ++k) Wreg[k] = W[(size_t)k * 256 + w * 64 + lane];
  float bv = bias[lane];
  int ngroups = (N + 3) >> 2;
  for (int g = blockIdx.x; g < ngroups; g += gridDim.x) {
    int n0 = g * 4;
    __syncthreads();
    {
      int nn = n0 + w;
      if (nn < N) {
        ushort4 u = ((const ushort4*)(agg + (size_t)nn * 256))[t & 63];
        float4 f;
        f.x = __bfloat162float(*(__hip_bfloat16*)&u.x);
        f.y = __bfloat162float(*(__hip_bfloat16*)&u.y);
        f.z = __bfloat162float(*(__hip_bfloat16*)&u.z);
        f.w = __bfloat162float(*(__hip_bfloat16*)&u.w);
        *(float4*)&aggL[w][(t & 63) * 4] = f;
      } else {
        *(float4*)&aggL[w][(t & 63) * 4] = make_float4(0.f, 0.f, 0.f, 0.f);
      }
    }
    __syncthreads();
    float acc0 = 0.f, acc1 = 0.f, acc2 = 0.f, acc3 = 0.f;
#pragma unroll
    for (int k4 = 0; k4 < 16; ++k4) {
      float4 av0 = *(const float4*)&aggL[0][w * 64 + k4 * 4];
      float4 av1 = *(const float4*)&aggL[1][w * 64 + k4 * 4];
      float4 av2 = *(const float4*)&aggL[2][w * 64 + k4 * 4];
      float4 av3 = *(const float4*)&aggL[3][w * 64 + k4 * 4];
      float w0 = Wreg[k4 * 4 + 0], w1 = Wreg[k4 * 4 + 1];
      float w2 = Wreg[k4 * 4 + 2], w3 = Wreg[k4 * 4 + 3];
      acc0 = fmaf(av0.x, w0, acc0); acc0 = fmaf(av0.y, w1, acc0);
      acc0 = fmaf(av0.z, w2, acc0); acc0 = fmaf(av0.w, w3, acc0);
      acc1 = fmaf(av1.x, w0, acc1); acc1 = fmaf(av1.y, w1, acc1);
      acc1 = fmaf(av1.z, w2, acc1); acc1 = fmaf(av1.w, w3, acc1);
      acc2 = fmaf(av2.x, w0, acc2); acc2 = fmaf(av2.y, w1, acc2);
      acc2 = fmaf(av2.z, w2, acc2); acc2 = fmaf(av2.w, w3, acc2);
      acc3 = fmaf(av3.x, w0, acc3); acc3 = fmaf(av3.y, w1, acc3);
      acc3 = fmaf(av3.z, w2, acc3); acc3 = fmaf(av3.w, w3, acc3);
    }
    pL[w][0][lane] = acc0;
    pL[w][1][lane] = acc1;
    pL[w][2][lane] = acc2;
    pL[w][3][lane] = acc3;
    __syncthreads();
    int nn = n0 + w;
    if (nn < N) {
      out[(size_t)nn * 64 + lane] = pL[0][w][lane] + pL[1][w][lane] +
                                    pL[2][w][lane] + pL[3][w][lane] + bv;
    }
  }
}

extern "C" void kernel_launch(void* const* d_in, const int* in_sizes, int n_in,
                              void* d_out, int out_size, void* d_ws, size_t ws_size,
                              hipStream_t stream) {
  const float* meta_x = (const float*)d_in[0];
  const int* ei = (const int*)d_in[1];  // int32 edge index [2,E] flat
  const float* W = (const float*)d_in[2];
  const float* att_src = (const float*)d_in[3];
  const float* att_dst = (const float*)d_in[4];
  const float* bias = (const float*)d_in[5];
  float* out = (float*)d_out;

  int N = in_sizes[0] / 64;
  int E = in_sizes[1] / 2;
  int ET = E + N;
  int ntiles = (N + 255) / 256;
  int chunkN = (N + 7) / 8;

  char* ws = (char*)d_ws;
  size_t off = 0;
  auto alloc = [&](size_t bytes) {
    size_t o = off;
    off += (bytes + 255) & ~(size_t)255;
    return o;
  };
  size_t o_wsrc = alloc(64 * 4 * sizeof(float));
  size_t o_wdst = alloc(64 * 4 * sizeof(float));
  size_t o_asrc = alloc((size_t)N * 4 * sizeof(float));
  size_t o_adst = alloc((size_t)N * 4 * sizeof(float));
  size_t o_cnt = alloc((size_t)ntiles * 256 * sizeof(int));  // padded to tiles
  size_t o_row = alloc(((size_t)N + 1) * sizeof(int));
  size_t o_cur = alloc((size_t)N * sizeof(int));
  size_t o_srt = alloc((size_t)ET * sizeof(int));
  size_t o_ts = alloc((size_t)ntiles * sizeof(int));
  size_t o_cp = alloc((size_t)256 * chunkN * sizeof(int));        // 6.4 MB partials
  size_t o_xh = alloc((size_t)N * 64 * sizeof(__hip_bfloat16));   // 6.4 MB
  size_t o_agg = alloc((size_t)N * 256 * sizeof(__hip_bfloat16)); // 25.6 MB
  (void)ws_size;

  float* wsrc = (float*)(ws + o_wsrc);
  float* wdst = (float*)(ws + o_wdst);
  float4* asrc4 = (float4*)(ws + o_asrc);
  float4* adst4 = (float4*)(ws + o_adst);
  int* cnt = (int*)(ws + o_cnt);
  int* row = (int*)(ws + o_row);
  int* cur = (int*)(ws + o_cur);
  int* srt = (int*)(ws + o_srt);
  int* tsum = (int*)(ws + o_ts);
  int* cntpart = (int*)(ws + o_cp);
  __hip_bfloat16* xh = (__hip_bfloat16*)(ws + o_xh);
  __hip_bfloat16* aggp = (__hip_bfloat16*)(ws + o_agg);

  int n4 = ntiles * 64;
  prep_kernel<<<64, 256, 0, stream>>>((int4*)cnt, n4, N, W, att_src, att_dst, wsrc, wdst);

  bool ldsHist = ((E & 3) == 0) && (chunkN <= MAXCHUNK);
  if (ldsHist) {
    histpart_kernel<<<256, 256, 0, stream>>>(ei, cntpart, E, N, chunkN);
    nattn_kernel<<<(N + 3) / 4, 256, 0, stream>>>(meta_x, (const float4*)wsrc,
                                                  (const float4*)wdst, asrc4, adst4, xh, N);
    merge_kernel<<<ntiles, 256, 0, stream>>>(cntpart, cnt, N, chunkN, ntiles * 256);
  } else {
    nattn_kernel<<<(N + 3) / 4, 256, 0, stream>>>(meta_x, (const float4*)wsrc,
                                                  (const float4*)wdst, asrc4, adst4, xh, N);
    hist_kernel<<<(E + 255) / 256, 256, 0, stream>>>(ei, cnt, E);
  }

  if (ntiles <= 256) {
    scanABC_kernel<<<ntiles, 256, 0, stream>>>(cnt, row, cur, N, ntiles);
  } else {
    scanA_kernel<<<ntiles, 256, 0, stream>>>(cnt, tsum, N);
    scanB_kernel<<<1, 256, 0, stream>>>(tsum, ntiles);
    scanC_kernel<<<ntiles, 256, 0, stream>>>(cnt, tsum, row, cur, N);
  }

  if ((E & 3) == 0) {
    scatter8_kernel<<<2048, 256, 0, stream>>>(ei, cur, srt, E, N);
  } else {
    scatter_kernel<<<(ET + 255) / 256, 256, 0, stream>>>(ei, cur, srt, E, N);
  }

  agg_kernel<<<(N + 3) / 4, 256, 0, stream>>>(srt, row, asrc4, adst4, xh, aggp, N);
  int ngroups = (N + 3) / 4;
  int pgrid = ngroups < 1024 ? ngroups : 1024;
  proj_kernel<<<pgrid, 256, 0, stream>>>(aggp, W, bias, out, N);
}